// Round 2
// baseline (1427.923 us; speedup 1.0000x reference)
//
#include <hip/hip_runtime.h>
#include <float.h>
#include <math.h>

#define NN 100000
#define NE 1600000
#define D 64
#define LEAK 0.2f

// --- K2: edge scatter-add.  16 threads per edge, float4 each -> 64 dims.
__global__ __launch_bounds__(256) void k_edge(const int* __restrict__ rows,
                                              const int* __restrict__ cols,
                                              const float* __restrict__ vals,
                                              const float* __restrict__ embeds,
                                              float* __restrict__ agg) {
    int t = blockIdx.x * 256 + threadIdx.x;
    int e = t >> 4;
    int q = t & 15;
    if (e >= NE) return;
    int r = rows[e];
    int c = cols[e];
    float v = vals[e];
    const float4 x = *(const float4*)(embeds + (long)c * D + q * 4);
    float* dst = agg + (long)r * D + q * 4;
    unsafeAtomicAdd(dst + 0, v * x.x);
    unsafeAtomicAdd(dst + 1, v * x.y);
    unsafeAtomicAdd(dst + 2, v * x.z);
    unsafeAtomicAdd(dst + 3, v * x.w);
}

// --- K3: scores s[n] = dot(agg[n,:], w).  One wave (64 lanes) per node.
__global__ __launch_bounds__(256) void k_score(const float* __restrict__ agg,
                                               const float* __restrict__ w,
                                               float* __restrict__ s) {
    int wave = (blockIdx.x * 256 + threadIdx.x) >> 6;
    int lane = threadIdx.x & 63;
    if (wave >= NN) return;
    float v = agg[(long)wave * D + lane] * w[lane];
    #pragma unroll
    for (int off = 32; off; off >>= 1) v += __shfl_down(v, off, 64);
    if (lane == 0) s[wave] = v;
}

// --- K4: softmax over all N scores, single block, 3 passes over 400KB.
__global__ __launch_bounds__(1024) void k_softmax(float* __restrict__ s) {
    __shared__ float red[16];
    int tid = threadIdx.x;
    int lane = tid & 63;
    int wv = tid >> 6;

    // pass 1: max
    float m = -FLT_MAX;
    for (int i = tid; i < NN; i += 1024) m = fmaxf(m, s[i]);
    #pragma unroll
    for (int off = 32; off; off >>= 1) m = fmaxf(m, __shfl_down(m, off, 64));
    if (lane == 0) red[wv] = m;
    __syncthreads();
    if (tid < 16) {
        float t = red[tid];
        #pragma unroll
        for (int off = 8; off; off >>= 1) t = fmaxf(t, __shfl_down(t, off, 16));
        if (tid == 0) red[0] = t;
    }
    __syncthreads();
    m = red[0];
    __syncthreads();

    // pass 2: sum of exp(s - m)
    float acc = 0.0f;
    for (int i = tid; i < NN; i += 1024) acc += expf(s[i] - m);
    #pragma unroll
    for (int off = 32; off; off >>= 1) acc += __shfl_down(acc, off, 64);
    if (lane == 0) red[wv] = acc;
    __syncthreads();
    if (tid < 16) {
        float t = red[tid];
        #pragma unroll
        for (int off = 8; off; off >>= 1) t += __shfl_down(t, off, 16);
        if (tid == 0) red[0] = t;
    }
    __syncthreads();
    float inv = 1.0f / red[0];

    // pass 3: overwrite s with normalized scores
    for (int i = tid; i < NN; i += 1024) s[i] = expf(s[i] - m) * inv;
}

// --- K5: out = leaky_relu(agg * score[n]), in place on d_out.
__global__ __launch_bounds__(256) void k_out(float* __restrict__ agg,
                                             const float* __restrict__ s) {
    int i = blockIdx.x * 256 + threadIdx.x;   // float4 index
    if (i >= NN * (D / 4)) return;
    int n = i >> 4;
    float sc = s[n];
    float4 x = ((float4*)agg)[i];
    x.x *= sc; x.y *= sc; x.z *= sc; x.w *= sc;
    x.x = x.x > 0.0f ? x.x : LEAK * x.x;
    x.y = x.y > 0.0f ? x.y : LEAK * x.y;
    x.z = x.z > 0.0f ? x.z : LEAK * x.z;
    x.w = x.w > 0.0f ? x.w : LEAK * x.w;
    ((float4*)agg)[i] = x;
}

extern "C" void kernel_launch(void* const* d_in, const int* in_sizes, int n_in,
                              void* d_out, int out_size, void* d_ws, size_t ws_size,
                              hipStream_t stream) {
    const int*   rows   = (const int*)d_in[0];
    const int*   cols   = (const int*)d_in[1];
    const float* vals   = (const float*)d_in[2];
    const float* embeds = (const float*)d_in[3];
    const float* w      = (const float*)d_in[4];
    float* out = (float*)d_out;          // doubles as agg buffer
    float* s   = (float*)d_ws;           // N score floats

    hipMemsetAsync(out, 0, (size_t)NN * D * sizeof(float), stream);

    k_edge<<<NE * 16 / 256, 256, 0, stream>>>(rows, cols, vals, embeds, out);
    k_score<<<NN * 64 / 256, 256, 0, stream>>>(out, w, s);
    k_softmax<<<1, 1024, 0, stream>>>(s);
    k_out<<<NN * D / 4 / 256, 256, 0, stream>>>(out, s);
}

// Round 3
// 400.964 us; speedup vs baseline: 3.5612x; 3.5612x over previous
//
#include <hip/hip_runtime.h>
#include <float.h>
#include <math.h>

#define NN 100000
#define NE 1600000
#define D 64
#define LEAK 0.2f

#define SCAN_CHUNK 2048                      // 256 threads x 8 elems
#define NOFF (NN + 1)                        // 100001 offsets
#define NBLK ((NOFF + SCAN_CHUNK - 1) / SCAN_CHUNK)  // 49

// ---------------- CSR-build path ----------------

// histogram: counts[r] = #edges with row r  (int atomics, 1.6M ops)
__global__ __launch_bounds__(256) void k_hist(const int* __restrict__ rows,
                                              int* __restrict__ cnt) {
    int e = blockIdx.x * 256 + threadIdx.x;
    if (e < NE) atomicAdd(&cnt[rows[e]], 1);
}

// scan phase A: per-block chunk sums
__global__ __launch_bounds__(256) void k_scanA(const int* __restrict__ cnt,
                                               int* __restrict__ partial) {
    int base = blockIdx.x * SCAN_CHUNK + threadIdx.x * 8;
    int s = 0;
    #pragma unroll
    for (int k = 0; k < 8; k++) { int i = base + k; if (i < NOFF) s += cnt[i]; }
    __shared__ int red[256];
    red[threadIdx.x] = s;
    __syncthreads();
    for (int off = 128; off; off >>= 1) {
        if (threadIdx.x < off) red[threadIdx.x] += red[threadIdx.x + off];
        __syncthreads();
    }
    if (threadIdx.x == 0) partial[blockIdx.x] = red[0];
}

// scan phase B: exclusive scan of NBLK partials (tiny, serial)
__global__ void k_scanB(int* __restrict__ partial) {
    int acc = 0;
    for (int i = 0; i < NBLK; i++) { int t = partial[i]; partial[i] = acc; acc += t; }
}

// scan phase C: full exclusive scan, in place (data==cnt buffer), also fills cursor
__global__ __launch_bounds__(256) void k_scanC(int* data,
                                               const int* __restrict__ partial,
                                               int* __restrict__ cursor) {
    __shared__ int sdata[256];
    int tid = threadIdx.x;
    int base = blockIdx.x * SCAN_CHUNK + tid * 8;
    int v[8]; int s = 0;
    #pragma unroll
    for (int k = 0; k < 8; k++) { int i = base + k; v[k] = (i < NOFF) ? data[i] : 0; s += v[k]; }
    sdata[tid] = s;
    __syncthreads();
    for (int off = 1; off < 256; off <<= 1) {
        int t = 0;
        if (tid >= off) t = sdata[tid - off];
        __syncthreads();
        sdata[tid] += t;
        __syncthreads();
    }
    int excl = sdata[tid] - s + partial[blockIdx.x];
    #pragma unroll
    for (int k = 0; k < 8; k++) {
        int i = base + k;
        if (i < NOFF) {
            data[i] = excl;
            if (i < NN) cursor[i] = excl;
            excl += v[k];
        }
    }
}

// scatter edges into row-sorted (col,val) packed pairs
__global__ __launch_bounds__(256) void k_scatter(const int* __restrict__ rows,
                                                 const int* __restrict__ cols,
                                                 const float* __restrict__ vals,
                                                 int* __restrict__ cursor,
                                                 unsigned long long* __restrict__ pairs) {
    int e = blockIdx.x * 256 + threadIdx.x;
    if (e >= NE) return;
    int r = rows[e];
    int pos = atomicAdd(&cursor[r], 1);
    unsigned long long p = (unsigned long long)(unsigned int)cols[e]
                         | ((unsigned long long)__float_as_uint(vals[e]) << 32);
    pairs[pos] = p;
}

// segmented sum: one wave per node, lane = dim. Also fuses the score dot-product.
__global__ __launch_bounds__(256) void k_agg(const unsigned long long* __restrict__ pairs,
                                             const int* __restrict__ offs,
                                             const float* __restrict__ embeds,
                                             const float* __restrict__ w,
                                             float* __restrict__ agg,
                                             float* __restrict__ s) {
    int node = (blockIdx.x * 256 + threadIdx.x) >> 6;
    int lane = threadIdx.x & 63;
    if (node >= NN) return;
    int st = offs[node], en = offs[node + 1];
    float acc = 0.0f;
    for (int j = st; j < en; j++) {
        unsigned long long p = pairs[j];
        int c = (int)(unsigned int)(p & 0xffffffffu);
        float v = __uint_as_float((unsigned int)(p >> 32));
        acc = fmaf(v, embeds[(long)c * D + lane], acc);
    }
    agg[(long)node * D + lane] = acc;
    float t = acc * w[lane];
    #pragma unroll
    for (int off = 32; off; off >>= 1) t += __shfl_down(t, off, 64);
    if (lane == 0) s[node] = t;
}

// ---------------- fallback atomic path (ws too small) ----------------

__global__ __launch_bounds__(256) void k_edge(const int* __restrict__ rows,
                                              const int* __restrict__ cols,
                                              const float* __restrict__ vals,
                                              const float* __restrict__ embeds,
                                              float* __restrict__ agg) {
    int t = blockIdx.x * 256 + threadIdx.x;
    int e = t >> 4;
    int q = t & 15;
    if (e >= NE) return;
    int r = rows[e];
    int c = cols[e];
    float v = vals[e];
    const float4 x = *(const float4*)(embeds + (long)c * D + q * 4);
    float* dst = agg + (long)r * D + q * 4;
    unsafeAtomicAdd(dst + 0, v * x.x);
    unsafeAtomicAdd(dst + 1, v * x.y);
    unsafeAtomicAdd(dst + 2, v * x.z);
    unsafeAtomicAdd(dst + 3, v * x.w);
}

__global__ __launch_bounds__(256) void k_score(const float* __restrict__ agg,
                                               const float* __restrict__ w,
                                               float* __restrict__ s) {
    int node = (blockIdx.x * 256 + threadIdx.x) >> 6;
    int lane = threadIdx.x & 63;
    if (node >= NN) return;
    float v = agg[(long)node * D + lane] * w[lane];
    #pragma unroll
    for (int off = 32; off; off >>= 1) v += __shfl_down(v, off, 64);
    if (lane == 0) s[node] = v;
}

// ---------------- shared tail kernels ----------------

__global__ __launch_bounds__(1024) void k_softmax(float* __restrict__ s) {
    __shared__ float red[16];
    int tid = threadIdx.x;
    int lane = tid & 63;
    int wv = tid >> 6;

    float m = -FLT_MAX;
    for (int i = tid; i < NN; i += 1024) m = fmaxf(m, s[i]);
    #pragma unroll
    for (int off = 32; off; off >>= 1) m = fmaxf(m, __shfl_down(m, off, 64));
    if (lane == 0) red[wv] = m;
    __syncthreads();
    if (tid < 16) {
        float t = red[tid];
        #pragma unroll
        for (int off = 8; off; off >>= 1) t = fmaxf(t, __shfl_down(t, off, 16));
        if (tid == 0) red[0] = t;
    }
    __syncthreads();
    m = red[0];
    __syncthreads();

    float acc = 0.0f;
    for (int i = tid; i < NN; i += 1024) acc += expf(s[i] - m);
    #pragma unroll
    for (int off = 32; off; off >>= 1) acc += __shfl_down(acc, off, 64);
    if (lane == 0) red[wv] = acc;
    __syncthreads();
    if (tid < 16) {
        float t = red[tid];
        #pragma unroll
        for (int off = 8; off; off >>= 1) t += __shfl_down(t, off, 16);
        if (tid == 0) red[0] = t;
    }
    __syncthreads();
    float inv = 1.0f / red[0];

    for (int i = tid; i < NN; i += 1024) s[i] = expf(s[i] - m) * inv;
}

__global__ __launch_bounds__(256) void k_out(float* __restrict__ agg,
                                             const float* __restrict__ s) {
    int i = blockIdx.x * 256 + threadIdx.x;   // float4 index
    if (i >= NN * (D / 4)) return;
    int n = i >> 4;
    float sc = s[n];
    float4 x = ((float4*)agg)[i];
    x.x *= sc; x.y *= sc; x.z *= sc; x.w *= sc;
    x.x = x.x > 0.0f ? x.x : LEAK * x.x;
    x.y = x.y > 0.0f ? x.y : LEAK * x.y;
    x.z = x.z > 0.0f ? x.z : LEAK * x.z;
    x.w = x.w > 0.0f ? x.w : LEAK * x.w;
    ((float4*)agg)[i] = x;
}

extern "C" void kernel_launch(void* const* d_in, const int* in_sizes, int n_in,
                              void* d_out, int out_size, void* d_ws, size_t ws_size,
                              hipStream_t stream) {
    const int*   rows   = (const int*)d_in[0];
    const int*   cols   = (const int*)d_in[1];
    const float* vals   = (const float*)d_in[2];
    const float* embeds = (const float*)d_in[3];
    const float* w      = (const float*)d_in[4];
    float* out = (float*)d_out;              // doubles as agg buffer

    // ws layout
    char* wsb = (char*)d_ws;
    float* s       = (float*)(wsb);                         // 400 KB
    int*   offs    = (int*)  (wsb + (1u << 19));            // 512 KB: 100001 ints
    int*   cursor  = (int*)  (wsb + (1u << 20));            // 1.0 MB: 100000 ints
    int*   partial = (int*)  (wsb + (3u << 19));            // 1.5 MB: 49 ints
    unsigned long long* pairs = (unsigned long long*)(wsb + (2u << 20)); // 2MB..14.8MB

    const size_t ws_needed = (2u << 20) + (size_t)NE * 8;   // ~14.8 MB

    if (ws_size >= ws_needed) {
        // --- CSR path, no float atomics ---
        hipMemsetAsync(offs, 0, NOFF * sizeof(int), stream);
        k_hist   <<<(NE + 255) / 256, 256, 0, stream>>>(rows, offs);
        k_scanA  <<<NBLK, 256, 0, stream>>>(offs, partial);
        k_scanB  <<<1, 1, 0, stream>>>(partial);
        k_scanC  <<<NBLK, 256, 0, stream>>>(offs, partial, cursor);
        k_scatter<<<(NE + 255) / 256, 256, 0, stream>>>(rows, cols, vals, cursor, pairs);
        k_agg    <<<(NN * 64 + 255) / 256, 256, 0, stream>>>(pairs, offs, embeds, w, out, s);
    } else {
        // --- fallback: atomic scatter ---
        hipMemsetAsync(out, 0, (size_t)NN * D * sizeof(float), stream);
        k_edge <<<NE * 16 / 256, 256, 0, stream>>>(rows, cols, vals, embeds, out);
        k_score<<<(NN * 64 + 255) / 256, 256, 0, stream>>>(out, w, s);
    }

    k_softmax<<<1, 1024, 0, stream>>>(s);
    k_out<<<(NN * D / 4 + 255) / 256, 256, 0, stream>>>(out, s);
}

// Round 4
// 356.138 us; speedup vs baseline: 4.0095x; 1.1259x over previous
//
#include <hip/hip_runtime.h>
#include <float.h>
#include <math.h>

#define NN 100000
#define NE 1600000
#define D 64
#define LEAK 0.2f

#define SCAN_CHUNK 2048                      // 256 threads x 8 elems
#define NOFF (NN + 1)                        // 100001 offsets
#define NBLK ((NOFF + SCAN_CHUNK - 1) / SCAN_CHUNK)  // 49

typedef unsigned long long ull;

// ordered-int encoding of float for atomicMax over mixed signs
__device__ __forceinline__ unsigned ford(float f) {
    unsigned u = __float_as_uint(f);
    return (u & 0x80000000u) ? ~u : (u | 0x80000000u);
}
__device__ __forceinline__ float funord(unsigned o) {
    return __uint_as_float((o & 0x80000000u) ? (o & 0x7fffffffu) : ~o);
}

// ---------------- CSR build ----------------

__global__ __launch_bounds__(256) void k_hist(const int* __restrict__ rows,
                                              int* __restrict__ cnt) {
    int e = blockIdx.x * 256 + threadIdx.x;
    if (e < NE) atomicAdd(&cnt[rows[e]], 1);
}

__global__ __launch_bounds__(256) void k_scanA(const int* __restrict__ cnt,
                                               int* __restrict__ partial) {
    int base = blockIdx.x * SCAN_CHUNK + threadIdx.x * 8;
    int s = 0;
    #pragma unroll
    for (int k = 0; k < 8; k++) { int i = base + k; if (i < NOFF) s += cnt[i]; }
    __shared__ int red[256];
    red[threadIdx.x] = s;
    __syncthreads();
    for (int off = 128; off; off >>= 1) {
        if (threadIdx.x < off) red[threadIdx.x] += red[threadIdx.x + off];
        __syncthreads();
    }
    if (threadIdx.x == 0) partial[blockIdx.x] = red[0];
}

__global__ void k_scanB(int* __restrict__ partial) {
    int acc = 0;
    for (int i = 0; i < NBLK; i++) { int t = partial[i]; partial[i] = acc; acc += t; }
}

__global__ __launch_bounds__(256) void k_scanC(int* data,
                                               const int* __restrict__ partial,
                                               int* __restrict__ cursor) {
    __shared__ int sdata[256];
    int tid = threadIdx.x;
    int base = blockIdx.x * SCAN_CHUNK + tid * 8;
    int v[8]; int s = 0;
    #pragma unroll
    for (int k = 0; k < 8; k++) { int i = base + k; v[k] = (i < NOFF) ? data[i] : 0; s += v[k]; }
    sdata[tid] = s;
    __syncthreads();
    for (int off = 1; off < 256; off <<= 1) {
        int t = 0;
        if (tid >= off) t = sdata[tid - off];
        __syncthreads();
        sdata[tid] += t;
        __syncthreads();
    }
    int excl = sdata[tid] - s + partial[blockIdx.x];
    #pragma unroll
    for (int k = 0; k < 8; k++) {
        int i = base + k;
        if (i < NOFF) {
            data[i] = excl;
            if (i < NN) cursor[i] = excl;
            excl += v[k];
        }
    }
}

__global__ __launch_bounds__(256) void k_scatter(const int* __restrict__ rows,
                                                 const int* __restrict__ cols,
                                                 const float* __restrict__ vals,
                                                 int* __restrict__ cursor,
                                                 ull* __restrict__ pairs) {
    int e = blockIdx.x * 256 + threadIdx.x;
    if (e >= NE) return;
    int r = rows[e];
    int pos = atomicAdd(&cursor[r], 1);
    ull p = (ull)(unsigned)cols[e] | ((ull)__float_as_uint(vals[e]) << 32);
    pairs[pos] = p;
}

// segmented sum: wave per node, lane = dim. Coalesced 64-edge chunk load +
// shfl broadcast -> all gathers independent, pipelineable. Fuses score dot.
__global__ __launch_bounds__(256) void k_agg(const ull* __restrict__ pairs,
                                             const int* __restrict__ offs,
                                             const float* __restrict__ embeds,
                                             const float* __restrict__ w,
                                             float* __restrict__ agg,
                                             float* __restrict__ s) {
    int node = (blockIdx.x * 256 + threadIdx.x) >> 6;
    int lane = threadIdx.x & 63;
    if (node >= NN) return;
    int st = offs[node], en = offs[node + 1];
    float acc = 0.0f;
    for (int base = st; base < en; base += 64) {
        int nk = en - base; if (nk > 64) nk = 64;
        ull p = (base + lane < en) ? pairs[base + lane] : 0ull;
        unsigned clo = (unsigned)p;
        unsigned vhi = (unsigned)(p >> 32);
        #pragma unroll 8
        for (int j = 0; j < nk; ++j) {
            int c   = __shfl((int)clo, j, 64);
            float v = __uint_as_float((unsigned)__shfl((int)vhi, j, 64));
            acc = fmaf(v, embeds[(long)c * D + lane], acc);
        }
    }
    agg[(long)node * D + lane] = acc;
    float t = acc * w[lane];
    #pragma unroll
    for (int off = 32; off; off >>= 1) t += __shfl_down(t, off, 64);
    if (lane == 0) s[node] = t;
}

// ---------------- softmax reductions (grid-wide, atomic) ----------------

__global__ __launch_bounds__(256) void k_smax(const float* __restrict__ s,
                                              unsigned* __restrict__ omax) {
    int i = blockIdx.x * 256 + threadIdx.x;
    float m = (i < NN) ? s[i] : -FLT_MAX;
    #pragma unroll
    for (int off = 32; off; off >>= 1) m = fmaxf(m, __shfl_down(m, off, 64));
    if ((threadIdx.x & 63) == 0) atomicMax(omax, ford(m));
}

__global__ __launch_bounds__(256) void k_ssum(const float* __restrict__ s,
                                              const unsigned* __restrict__ omax,
                                              float* __restrict__ sum) {
    float m = funord(*omax);
    int i = blockIdx.x * 256 + threadIdx.x;
    float a = (i < NN) ? expf(s[i] - m) : 0.0f;
    #pragma unroll
    for (int off = 32; off; off >>= 1) a += __shfl_down(a, off, 64);
    if ((threadIdx.x & 63) == 0) atomicAdd(sum, a);
}

// out = leaky_relu(agg * softmax(s)[n]); normalization folded in.
__global__ __launch_bounds__(256) void k_out(float* __restrict__ agg,
                                             const float* __restrict__ s,
                                             const unsigned* __restrict__ omax,
                                             const float* __restrict__ sum) {
    int i = blockIdx.x * 256 + threadIdx.x;   // float4 index
    if (i >= NN * (D / 4)) return;
    int n = i >> 4;
    float m = funord(*omax);
    float sc = expf(s[n] - m) / (*sum);
    float4 x = ((float4*)agg)[i];
    x.x *= sc; x.y *= sc; x.z *= sc; x.w *= sc;
    x.x = x.x > 0.0f ? x.x : LEAK * x.x;
    x.y = x.y > 0.0f ? x.y : LEAK * x.y;
    x.z = x.z > 0.0f ? x.z : LEAK * x.z;
    x.w = x.w > 0.0f ? x.w : LEAK * x.w;
    ((float4*)agg)[i] = x;
}

// ---------------- fallback atomic path (ws too small) ----------------

__global__ __launch_bounds__(256) void k_edge(const int* __restrict__ rows,
                                              const int* __restrict__ cols,
                                              const float* __restrict__ vals,
                                              const float* __restrict__ embeds,
                                              float* __restrict__ agg) {
    int t = blockIdx.x * 256 + threadIdx.x;
    int e = t >> 4;
    int q = t & 15;
    if (e >= NE) return;
    int r = rows[e];
    int c = cols[e];
    float v = vals[e];
    const float4 x = *(const float4*)(embeds + (long)c * D + q * 4);
    float* dst = agg + (long)r * D + q * 4;
    unsafeAtomicAdd(dst + 0, v * x.x);
    unsafeAtomicAdd(dst + 1, v * x.y);
    unsafeAtomicAdd(dst + 2, v * x.z);
    unsafeAtomicAdd(dst + 3, v * x.w);
}

__global__ __launch_bounds__(256) void k_score(const float* __restrict__ agg,
                                               const float* __restrict__ w,
                                               float* __restrict__ s) {
    int node = (blockIdx.x * 256 + threadIdx.x) >> 6;
    int lane = threadIdx.x & 63;
    if (node >= NN) return;
    float v = agg[(long)node * D + lane] * w[lane];
    #pragma unroll
    for (int off = 32; off; off >>= 1) v += __shfl_down(v, off, 64);
    if (lane == 0) s[node] = v;
}

extern "C" void kernel_launch(void* const* d_in, const int* in_sizes, int n_in,
                              void* d_out, int out_size, void* d_ws, size_t ws_size,
                              hipStream_t stream) {
    const int*   rows   = (const int*)d_in[0];
    const int*   cols   = (const int*)d_in[1];
    const float* vals   = (const float*)d_in[2];
    const float* embeds = (const float*)d_in[3];
    const float* w      = (const float*)d_in[4];
    float* out = (float*)d_out;              // doubles as agg buffer

    // ws layout
    char* wsb = (char*)d_ws;
    float*    s       = (float*)(wsb);                       // 0     .. 400KB
    int*      offs    = (int*)  (wsb + (1u << 19));          // 512KB .. 912KB
    int*      cursor  = (int*)  (wsb + (1u << 20));          // 1MB   .. 1.4MB
    int*      partial = (int*)  (wsb + 3 * (1u << 19));      // 1.5MB
    unsigned* omax    = (unsigned*)(wsb + 7 * (1u << 18));   // 1.75MB
    float*    sum     = (float*)   (wsb + 7 * (1u << 18) + 4);
    ull*      pairs   = (ull*)  (wsb + (2u << 20));          // 2MB .. 14.8MB

    const size_t ws_needed = (2u << 20) + (size_t)NE * 8;

    const int nb_nodes = (NN * 64 + 255) / 256;
    const int nb_sc    = (NN + 255) / 256;

    if (ws_size >= ws_needed) {
        hipMemsetAsync(offs, 0, NOFF * sizeof(int), stream);
        hipMemsetAsync(omax, 0, 8, stream);   // omax=0 (< ord of any float), sum=0.0f
        k_hist   <<<(NE + 255) / 256, 256, 0, stream>>>(rows, offs);
        k_scanA  <<<NBLK, 256, 0, stream>>>(offs, partial);
        k_scanB  <<<1, 1, 0, stream>>>(partial);
        k_scanC  <<<NBLK, 256, 0, stream>>>(offs, partial, cursor);
        k_scatter<<<(NE + 255) / 256, 256, 0, stream>>>(rows, cols, vals, cursor, pairs);
        k_agg    <<<nb_nodes, 256, 0, stream>>>(pairs, offs, embeds, w, out, s);
    } else {
        hipMemsetAsync(out, 0, (size_t)NN * D * sizeof(float), stream);
        hipMemsetAsync(omax, 0, 8, stream);
        k_edge <<<NE * 16 / 256, 256, 0, stream>>>(rows, cols, vals, embeds, out);
        k_score<<<nb_nodes, 256, 0, stream>>>(out, w, s);
    }

    k_smax<<<nb_sc, 256, 0, stream>>>(s, omax);
    k_ssum<<<nb_sc, 256, 0, stream>>>(s, omax, sum);
    k_out <<<(NN * D / 4 + 255) / 256, 256, 0, stream>>>(out, s, omax, sum);
}

// Round 6
// 344.344 us; speedup vs baseline: 4.1468x; 1.0342x over previous
//
#include <hip/hip_runtime.h>
#include <float.h>
#include <math.h>

#define NN 100000
#define NE 1600000
#define D 64
#define LEAK 0.2f

#define SCAN_CHUNK 2048                      // 256 threads x 8 elems
#define NOFF (NN + 1)                        // 100001 offsets
#define NBLK ((NOFF + SCAN_CHUNK - 1) / SCAN_CHUNK)  // 49

typedef unsigned long long ull;

// ordered-int encoding of float for atomicMax over mixed signs
__device__ __forceinline__ unsigned ford(float f) {
    unsigned u = __float_as_uint(f);
    return (u & 0x80000000u) ? ~u : (u | 0x80000000u);
}
__device__ __forceinline__ float funord(unsigned o) {
    return __uint_as_float((o & 0x80000000u) ? (o & 0x7fffffffu) : ~o);
}

// ---------------- CSR build ----------------
// STR = counter stride in ints (16 => one counter per 64B line, kills
// per-line atomic serialization at the coherence point; 1 => compact).

// histogram: 4 edges per thread (int4 load), independent atomics
__global__ __launch_bounds__(256) void k_hist(const int4* __restrict__ rows4,
                                              int* __restrict__ cnt, int STR) {
    int t = blockIdx.x * 256 + threadIdx.x;
    if (t >= NE / 4) return;
    int4 r = rows4[t];
    atomicAdd(&cnt[r.x * STR], 1);
    atomicAdd(&cnt[r.y * STR], 1);
    atomicAdd(&cnt[r.z * STR], 1);
    atomicAdd(&cnt[r.w * STR], 1);
}

__global__ __launch_bounds__(256) void k_scanA(const int* __restrict__ cnt,
                                               int* __restrict__ partial, int STR) {
    int base = blockIdx.x * SCAN_CHUNK + threadIdx.x * 8;
    int s = 0;
    #pragma unroll
    for (int k = 0; k < 8; k++) { int i = base + k; if (i < NOFF) s += cnt[i * STR]; }
    __shared__ int red[256];
    red[threadIdx.x] = s;
    __syncthreads();
    for (int off = 128; off; off >>= 1) {
        if (threadIdx.x < off) red[threadIdx.x] += red[threadIdx.x + off];
        __syncthreads();
    }
    if (threadIdx.x == 0) partial[blockIdx.x] = red[0];
}

__global__ void k_scanB(int* __restrict__ partial) {
    int acc = 0;
    for (int i = 0; i < NBLK; i++) { int t = partial[i]; partial[i] = acc; acc += t; }
}

// exclusive scan: reads padded cnt, writes COMPACT offs + PADDED cursor
__global__ __launch_bounds__(256) void k_scanC(const int* __restrict__ cnt,
                                               const int* __restrict__ partial,
                                               int* __restrict__ offs,
                                               int* __restrict__ cursor, int STR) {
    __shared__ int sdata[256];
    int tid = threadIdx.x;
    int base = blockIdx.x * SCAN_CHUNK + tid * 8;
    int v[8]; int s = 0;
    #pragma unroll
    for (int k = 0; k < 8; k++) { int i = base + k; v[k] = (i < NOFF) ? cnt[i * STR] : 0; s += v[k]; }
    sdata[tid] = s;
    __syncthreads();
    for (int off = 1; off < 256; off <<= 1) {
        int t = 0;
        if (tid >= off) t = sdata[tid - off];
        __syncthreads();
        sdata[tid] += t;
        __syncthreads();
    }
    int excl = sdata[tid] - s + partial[blockIdx.x];
    #pragma unroll
    for (int k = 0; k < 8; k++) {
        int i = base + k;
        if (i < NOFF) {
            offs[i] = excl;
            if (i < NN) cursor[i * STR] = excl;
            excl += v[k];
        }
    }
}

// scatter: 4 edges per thread, 4 independent atomic->store chains
__global__ __launch_bounds__(256) void k_scatter(const int4* __restrict__ rows4,
                                                 const int4* __restrict__ cols4,
                                                 const float4* __restrict__ vals4,
                                                 int* __restrict__ cursor,
                                                 ull* __restrict__ pairs, int STR) {
    int t = blockIdx.x * 256 + threadIdx.x;
    if (t >= NE / 4) return;
    int4 r = rows4[t];
    int4 c = cols4[t];
    float4 v = vals4[t];
    int p0 = atomicAdd(&cursor[r.x * STR], 1);
    int p1 = atomicAdd(&cursor[r.y * STR], 1);
    int p2 = atomicAdd(&cursor[r.z * STR], 1);
    int p3 = atomicAdd(&cursor[r.w * STR], 1);
    pairs[p0] = (ull)(unsigned)c.x | ((ull)__float_as_uint(v.x) << 32);
    pairs[p1] = (ull)(unsigned)c.y | ((ull)__float_as_uint(v.y) << 32);
    pairs[p2] = (ull)(unsigned)c.z | ((ull)__float_as_uint(v.z) << 32);
    pairs[p3] = (ull)(unsigned)c.w | ((ull)__float_as_uint(v.w) << 32);
}

// segmented sum: wave per node, lane = dim. Coalesced 64-edge chunk load +
// shfl broadcast -> independent gathers. Fuses score dot.
__global__ __launch_bounds__(256) void k_agg(const ull* __restrict__ pairs,
                                             const int* __restrict__ offs,
                                             const float* __restrict__ embeds,
                                             const float* __restrict__ w,
                                             float* __restrict__ agg,
                                             float* __restrict__ s) {
    int node = (blockIdx.x * 256 + threadIdx.x) >> 6;
    int lane = threadIdx.x & 63;
    if (node >= NN) return;
    int st = offs[node], en = offs[node + 1];
    float acc = 0.0f;
    for (int base = st; base < en; base += 64) {
        int nk = en - base; if (nk > 64) nk = 64;
        ull p = (base + lane < en) ? pairs[base + lane] : 0ull;
        unsigned clo = (unsigned)p;
        unsigned vhi = (unsigned)(p >> 32);
        #pragma unroll 8
        for (int j = 0; j < nk; ++j) {
            int c   = __shfl((int)clo, j, 64);
            float v = __uint_as_float((unsigned)__shfl((int)vhi, j, 64));
            acc = fmaf(v, embeds[(long)c * D + lane], acc);
        }
    }
    agg[(long)node * D + lane] = acc;
    float t = acc * w[lane];
    #pragma unroll
    for (int off = 32; off; off >>= 1) t += __shfl_down(t, off, 64);
    if (lane == 0) s[node] = t;
}

// ---------------- softmax reductions (block-reduce + 8-slot atomics) ----------------

__global__ __launch_bounds__(256) void k_smax(const float* __restrict__ s,
                                              unsigned* __restrict__ omax8) {
    __shared__ float red[4];
    int i = blockIdx.x * 256 + threadIdx.x;
    float m = (i < NN) ? s[i] : -FLT_MAX;
    #pragma unroll
    for (int off = 32; off; off >>= 1) m = fmaxf(m, __shfl_down(m, off, 64));
    int lane = threadIdx.x & 63, wv = threadIdx.x >> 6;
    if (lane == 0) red[wv] = m;
    __syncthreads();
    if (threadIdx.x == 0) {
        m = fmaxf(fmaxf(red[0], red[1]), fmaxf(red[2], red[3]));
        atomicMax(&omax8[blockIdx.x & 7], ford(m));
    }
}

__global__ __launch_bounds__(256) void k_ssum(const float* __restrict__ s,
                                              const unsigned* __restrict__ omax8,
                                              float* __restrict__ sums8) {
    __shared__ float red[4];
    float m = -FLT_MAX;
    #pragma unroll
    for (int k = 0; k < 8; k++) m = fmaxf(m, funord(omax8[k]));
    int i = blockIdx.x * 256 + threadIdx.x;
    float a = (i < NN) ? expf(s[i] - m) : 0.0f;
    #pragma unroll
    for (int off = 32; off; off >>= 1) a += __shfl_down(a, off, 64);
    int lane = threadIdx.x & 63, wv = threadIdx.x >> 6;
    if (lane == 0) red[wv] = a;
    __syncthreads();
    if (threadIdx.x == 0)
        atomicAdd(&sums8[blockIdx.x & 7], red[0] + red[1] + red[2] + red[3]);
}

__global__ __launch_bounds__(256) void k_out(float* __restrict__ agg,
                                             const float* __restrict__ s,
                                             const unsigned* __restrict__ omax8,
                                             const float* __restrict__ sums8) {
    int i = blockIdx.x * 256 + threadIdx.x;   // float4 index
    if (i >= NN * (D / 4)) return;
    int n = i >> 4;
    float m = -FLT_MAX, sum = 0.0f;
    #pragma unroll
    for (int k = 0; k < 8; k++) { m = fmaxf(m, funord(omax8[k])); sum += sums8[k]; }
    float sc = expf(s[n] - m) / sum;
    float4 x = ((float4*)agg)[i];
    x.x *= sc; x.y *= sc; x.z *= sc; x.w *= sc;
    x.x = x.x > 0.0f ? x.x : LEAK * x.x;
    x.y = x.y > 0.0f ? x.y : LEAK * x.y;
    x.z = x.z > 0.0f ? x.z : LEAK * x.z;
    x.w = x.w > 0.0f ? x.w : LEAK * x.w;
    ((float4*)agg)[i] = x;
}

// ---------------- fallback atomic path (ws too small) ----------------

__global__ __launch_bounds__(256) void k_edge(const int* __restrict__ rows,
                                              const int* __restrict__ cols,
                                              const float* __restrict__ vals,
                                              const float* __restrict__ embeds,
                                              float* __restrict__ agg) {
    int t = blockIdx.x * 256 + threadIdx.x;
    int e = t >> 4;
    int q = t & 15;
    if (e >= NE) return;
    int r = rows[e];
    int c = cols[e];
    float v = vals[e];
    const float4 x = *(const float4*)(embeds + (long)c * D + q * 4);
    float* dst = agg + (long)r * D + q * 4;
    unsafeAtomicAdd(dst + 0, v * x.x);
    unsafeAtomicAdd(dst + 1, v * x.y);
    unsafeAtomicAdd(dst + 2, v * x.z);
    unsafeAtomicAdd(dst + 3, v * x.w);
}

__global__ __launch_bounds__(256) void k_score(const float* __restrict__ agg,
                                               const float* __restrict__ w,
                                               float* __restrict__ s) {
    int node = (blockIdx.x * 256 + threadIdx.x) >> 6;
    int lane = threadIdx.x & 63;
    if (node >= NN) return;
    float v = agg[(long)node * D + lane] * w[lane];
    #pragma unroll
    for (int off = 32; off; off >>= 1) v += __shfl_down(v, off, 64);
    if (lane == 0) s[node] = v;
}

extern "C" void kernel_launch(void* const* d_in, const int* in_sizes, int n_in,
                              void* d_out, int out_size, void* d_ws, size_t ws_size,
                              hipStream_t stream) {
    const int*   rows   = (const int*)d_in[0];
    const int*   cols   = (const int*)d_in[1];
    const float* vals   = (const float*)d_in[2];
    const float* embeds = (const float*)d_in[3];
    const float* w      = (const float*)d_in[4];
    float* out = (float*)d_out;              // doubles as agg buffer

    char* wsb = (char*)d_ws;
    float*    s       = (float*)(wsb);                       // 0     .. 400KB
    int*      offs    = (int*)  (wsb + 0x80000);             // 512KB .. 912KB (compact)
    int*      partial = (int*)  (wsb + 0xF0000);             // 960KB (49 ints)
    unsigned* omax8   = (unsigned*)(wsb + 0xF4000);          // 32B
    float*    sums8   = (float*)   (wsb + 0xF4020);          // 32B, adjacent: one memset covers both

    // padded tier (STR=16): cnt 6.4MB @1MB, cursor 6.4MB @7.5MB, pairs @14MB
    // compact tier (STR=1): cnt 400KB @1MB, cursor 400KB @1.5MB, pairs @2MB
    const size_t need_pad = 0xE00000 + (size_t)NE * 8;       // ~27.5MB
    const size_t need_cmp = 0x200000 + (size_t)NE * 8;       // ~14.8MB

    const int nb_nodes = (NN * 64 + 255) / 256;
    const int nb_sc    = (NN + 255) / 256;
    const int nb_e4    = (NE / 4 + 255) / 256;

    // zero BOTH omax8 (8 u32) and sums8 (8 f32) every call — sums8 is
    // accumulated into by k_ssum, so leaving it would drift across replays.
    hipMemsetAsync(omax8, 0, 64, stream);

    if (ws_size >= need_cmp) {
        int STR;
        int *cnt, *cursor; ull* pairs;
        if (ws_size >= need_pad) {
            STR = 16;
            cnt    = (int*)(wsb + 0x100000);
            cursor = (int*)(wsb + 0x780000);
            pairs  = (ull*)(wsb + 0xE00000);
        } else {
            STR = 1;
            cnt    = (int*)(wsb + 0x100000);
            cursor = (int*)(wsb + 0x180000);
            pairs  = (ull*)(wsb + 0x200000);
        }
        hipMemsetAsync(cnt, 0, (size_t)NOFF * STR * sizeof(int), stream);
        k_hist   <<<nb_e4, 256, 0, stream>>>((const int4*)rows, cnt, STR);
        k_scanA  <<<NBLK, 256, 0, stream>>>(cnt, partial, STR);
        k_scanB  <<<1, 1, 0, stream>>>(partial);
        k_scanC  <<<NBLK, 256, 0, stream>>>(cnt, partial, offs, cursor, STR);
        k_scatter<<<nb_e4, 256, 0, stream>>>((const int4*)rows, (const int4*)cols,
                                             (const float4*)vals, cursor, pairs, STR);
        k_agg    <<<nb_nodes, 256, 0, stream>>>(pairs, offs, embeds, w, out, s);
    } else {
        hipMemsetAsync(out, 0, (size_t)NN * D * sizeof(float), stream);
        k_edge <<<NE * 16 / 256, 256, 0, stream>>>(rows, cols, vals, embeds, out);
        k_score<<<nb_nodes, 256, 0, stream>>>(out, w, s);
    }

    k_smax<<<nb_sc, 256, 0, stream>>>(s, omax8);
    k_ssum<<<nb_sc, 256, 0, stream>>>(s, omax8, sums8);
    k_out <<<(NN * D / 4 + 255) / 256, 256, 0, stream>>>(out, s, omax8, sums8);
}